// Round 6
// baseline (298.428 us; speedup 1.0000x reference)
//
#include <hip/hip_runtime.h>
#include <hip/hip_bf16.h>
#include <cstdint>
#include <cstddef>

#define NROWS 32768
#define DDIM  64
#define KDIM  8192
#define NSUB  128                 // 64-k subchunks per row
#define DELTA 3.0f                // covers 2*eps_bf16score + 2*bf16_ulp(storage)

typedef float  f32x4 __attribute__((ext_vector_type(4)));
typedef short  s16x8 __attribute__((ext_vector_type(8)));
typedef unsigned long long u64;

__device__ __forceinline__ uint32_t fmono(float f) {
    uint32_t u = __float_as_uint(f);
    return (u & 0x80000000u) ? ~u : (u | 0x80000000u);
}
__device__ __forceinline__ float bf2f(ushort s) {
    uint32_t u = (uint32_t)s << 16;
    return __uint_as_float(u);
}

// ================= fast path =================

// prep: LDS-tiled transpose w[d][k] -> wtb[k][d] (bf16), wsq[k] (serial fmaf order)
__global__ void __launch_bounds__(256)
vq_prep_w(const float* __restrict__ w, ushort* __restrict__ wtb,
          float* __restrict__ wsq) {
    __shared__ float tile[64][65];
    const int kbase = blockIdx.x * 64;
    const int t = threadIdx.x, wv = t >> 6, lane = t & 63;
#pragma unroll
    for (int it = 0; it < 16; ++it) {
        int d = it * 4 + wv;
        tile[lane][d] = w[(size_t)d * KDIM + kbase + lane];   // coalesced
    }
    __syncthreads();
#pragma unroll
    for (int it = 0; it < 16; ++it) {
        int kk = it * 4 + wv;
        float v = tile[kk][lane];                             // lane = d
        __hip_bfloat16 hb = __float2bfloat16(v);
        wtb[(size_t)(kbase + kk) * DDIM + lane] = *(ushort*)&hb;  // coalesced
    }
    if (wv == 0) {   // lane = k within tile; serial ascending-d fmaf
        float s = 0.f;
#pragma unroll
        for (int d = 0; d < DDIM; ++d) {
            float v = tile[lane][d];
            s = fmaf(v, v, s);
        }
        wsq[kbase + lane] = s;
    }
}

// prep: x -> bf16
__global__ void vq_prep_x(const float* __restrict__ x, ushort* __restrict__ xb) {
    int i = blockIdx.x * blockDim.x + threadIdx.x;   // one float4 per thread
    if (i >= NROWS * DDIM / 4) return;
    float4 v = ((const float4*)x)[i];
    ushort4 o;
    __hip_bfloat16 h;
    h = __float2bfloat16(v.x); o.x = *(ushort*)&h;
    h = __float2bfloat16(v.y); o.y = *(ushort*)&h;
    h = __float2bfloat16(v.z); o.z = *(ushort*)&h;
    h = __float2bfloat16(v.w); o.w = *(ushort*)&h;
    ((ushort4*)xb)[i] = o;
}

// pass A (restructured): swapped-operand MFMA => k is C's ROW dim => subchunk
// min is lane-local (16 regs) + 2 shfl across l4 groups.
// Block: 4 waves, no LDS. Wave = 32 rows x 256 k (2 row-tiles, 4 subchunks).
// Grid: (NROWS/128) x (KDIM/256).
__global__ void __launch_bounds__(256)
vq_scoreA(const ushort* __restrict__ xb, const ushort* __restrict__ wb,
          const float* __restrict__ wsq, ushort* __restrict__ lsub) {
    const int kg    = blockIdx.x & 31;            // 32 k-groups of 256
    const int rbase = (blockIdx.x >> 5) * 128;
    const int t = threadIdx.x, wv = t >> 6, lane = t & 63;
    const int l15 = lane & 15, l4 = lane >> 4;
    const int rw    = rbase + wv * 32;            // this wave's 32 rows
    const int kbase = kg * 256;

    // B operand = x (free idx = row): lane l15 = row-in-tile, elems = d
    s16x8 bfrag[2][2];
#pragma unroll
    for (int rt = 0; rt < 2; ++rt)
#pragma unroll
        for (int h = 0; h < 2; ++h)
            bfrag[rt][h] = *(const s16x8*)&xb[(size_t)(rw + rt * 16 + l15) * DDIM + h * 32 + l4 * 8];

    float subres[2][4];

#pragma unroll
    for (int sub = 0; sub < 4; ++sub) {
        const int kw = kbase + sub * 64;

        // A operand = w (free idx = k): lane l15 = k-in-tile, elems = d
        s16x8 afrag[4][2];
#pragma unroll
        for (int kt = 0; kt < 4; ++kt)
#pragma unroll
            for (int h = 0; h < 2; ++h)
                afrag[kt][h] = *(const s16x8*)&wb[(size_t)(kw + kt * 16 + l15) * DDIM + h * 32 + l4 * 8];

        // wsq for this lane's k values: k = kw + kt*16 + l4*4 + reg
        f32x4 wq[4];
#pragma unroll
        for (int kt = 0; kt < 4; ++kt)
            wq[kt] = *(const f32x4*)&wsq[kw + kt * 16 + l4 * 4];

        f32x4 acc[2][4];
#pragma unroll
        for (int rt = 0; rt < 2; ++rt)
#pragma unroll
            for (int kt = 0; kt < 4; ++kt) acc[rt][kt] = (f32x4)(0.f);

#pragma unroll
        for (int rt = 0; rt < 2; ++rt)
#pragma unroll
            for (int kt = 0; kt < 4; ++kt) {
                acc[rt][kt] = __builtin_amdgcn_mfma_f32_16x16x32_bf16(afrag[kt][0], bfrag[rt][0], acc[rt][kt], 0, 0, 0);
                acc[rt][kt] = __builtin_amdgcn_mfma_f32_16x16x32_bf16(afrag[kt][1], bfrag[rt][1], acc[rt][kt], 0, 0, 0);
            }

        // C layout: col (l15) = x-row, row (l4*4+reg) = k-in-tile.
        // Lane-local min over 16 k values, then 2 shfl across l4 groups.
#pragma unroll
        for (int rt = 0; rt < 2; ++rt) {
            float m = fmaf(-2.f, acc[rt][0][0], wq[0][0]);
#pragma unroll
            for (int kt = 0; kt < 4; ++kt)
#pragma unroll
                for (int r = 0; r < 4; ++r) {
                    if (kt == 0 && r == 0) continue;
                    m = fminf(m, fmaf(-2.f, acc[rt][kt][r], wq[kt][r]));
                }
            m = fminf(m, __shfl_xor(m, 16));
            m = fminf(m, __shfl_xor(m, 32));
            subres[rt][sub] = m;
        }
    }

    // pack + store: lane group l4==0 holds final mins; one ushort4 per row
    if (l4 == 0) {
#pragma unroll
        for (int rt = 0; rt < 2; ++rt) {
            ushort4 o;
            __hip_bfloat16 h;
            h = __float2bfloat16(subres[rt][0]); o.x = *(ushort*)&h;
            h = __float2bfloat16(subres[rt][1]); o.y = *(ushort*)&h;
            h = __float2bfloat16(subres[rt][2]); o.z = *(ushort*)&h;
            h = __float2bfloat16(subres[rt][3]); o.w = *(ushort*)&h;
            *(ushort4*)&lsub[(size_t)(rw + rt * 16 + l15) * NSUB + kg * 4] = o;
        }
    }
}

// finish: per-row (one wave): threshold -> ballot flags -> exact fp32 rescore of
// flagged subchunks -> fused gather.
__global__ void __launch_bounds__(256)
vq_finish(const float* __restrict__ x, const float* __restrict__ w,
          const float* __restrict__ wsq, const ushort* __restrict__ lsub,
          float* __restrict__ out) {
    const int wv = threadIdx.x >> 6, lane = threadIdx.x & 63;
    const int row = blockIdx.x * 4 + wv;

    ushort2 us = *(const ushort2*)&lsub[(size_t)row * NSUB + lane * 2];   // coalesced
    float v0 = bf2f(us.x), v1 = bf2f(us.y);
    float m = fminf(v0, v1);
#pragma unroll
    for (int o = 1; o < 64; o <<= 1) m = fminf(m, __shfl_xor(m, o));
    const float thr = m + DELTA;
    u64 b0 = __ballot(v0 <= thr);   // bit s -> subchunk 2s
    u64 b1 = __ballot(v1 <= thr);   // bit s -> subchunk 2s+1

    float4 xr[16];
    const float4* xp = (const float4*)(x + (size_t)row * DDIM);
#pragma unroll
    for (int i = 0; i < 16; ++i) xr[i] = xp[i];   // wave-uniform row

    u64 best = ~0ull;
#pragma unroll
    for (int half = 0; half < 2; ++half) {
        u64 b = half ? b1 : b0;
        while (b) {                      // wave-uniform loop
            int s = __ffsll(b) - 1;
            b &= b - 1;
            int kk = (s * 2 + half) * 64 + lane;
            float a0 = 0.f, a1 = 0.f, a2 = 0.f, a3 = 0.f;
#pragma unroll
            for (int i = 0; i < 16; ++i) {
                a0 = fmaf(xr[i].x, w[(size_t)(4 * i + 0) * KDIM + kk], a0);
                a1 = fmaf(xr[i].y, w[(size_t)(4 * i + 1) * KDIM + kk], a1);
                a2 = fmaf(xr[i].z, w[(size_t)(4 * i + 2) * KDIM + kk], a2);
                a3 = fmaf(xr[i].w, w[(size_t)(4 * i + 3) * KDIM + kk], a3);
            }
            float dot = (a0 + a1) + (a2 + a3);       // same order as round-1 (matched np)
            float sc  = fmaf(-2.f, dot, wsq[kk]);
            u64 key = ((u64)fmono(sc) << 32) | (unsigned)kk;
#pragma unroll
            for (int sh = 1; sh < 64; sh <<= 1) {
                u64 o = __shfl_xor(key, sh);
                key = (o < key) ? o : key;
            }
            best = (key < best) ? key : best;        // lowest-k tie-break
        }
    }
    const int bestk = (int)(best & 0xFFFFFFFFull);
    out[(size_t)row * DDIM + lane] = w[(size_t)lane * KDIM + bestk];  // fused gather
}

// ================= fallback (round-3 fp32 path, small ws) =================

#define BR 128
#define BK 128
#define DPH 32
typedef float v2f __attribute__((ext_vector_type(2)));

__global__ void fb_prep(const float* __restrict__ w, float* __restrict__ wt,
                        float* __restrict__ wsq) {
    int k = blockIdx.x * blockDim.x + threadIdx.x;
    if (k >= KDIM) return;
    float s = 0.f;
#pragma unroll
    for (int d = 0; d < DDIM; ++d) {
        float v = w[(size_t)d * KDIM + k];
        wt[(size_t)k * DDIM + d] = v;
        s = fmaf(v, v, s);
    }
    wsq[k] = s;
}
__global__ void fb_init(u64* __restrict__ keys) {
    int i = blockIdx.x * blockDim.x + threadIdx.x;
    if (i < NROWS) keys[i] = ~0ull;
}
__global__ void __launch_bounds__(256, 4)
fb_gemm(const float* __restrict__ x, const float* __restrict__ w,
        const float* __restrict__ wsq, u64* __restrict__ keys) {
    __shared__ float xT[DPH][BR];
    __shared__ float wl[DPH][BK];
    const int kblk  = blockIdx.x & (KDIM / BK - 1);
    const int rbase = (blockIdx.x >> 6) * BR;
    const int kbase = kblk * BK;
    const int t     = threadIdx.x;
    const int wave = t >> 6, lane = t & 63;
    const int rg = lane >> 3, cg = lane & 7;
    const int xoff = (wave >> 1) * 64 + rg * 8;
    const int coff = (wave & 1) * 64 + cg * 8;
    v2f acc[8][4];
#pragma unroll
    for (int i = 0; i < 8; ++i)
#pragma unroll
        for (int j = 0; j < 4; ++j) acc[i][j] = (v2f)(0.f);
#pragma unroll
    for (int p = 0; p < 2; ++p) {
        {
            const int row = t & 127, dgrp = t >> 7;
#pragma unroll
            for (int it = 0; it < 4; ++it) {
                const int dl = (dgrp + it * 2) * 4;
                float4 v = *(const float4*)&x[(size_t)(rbase + row) * DDIM + p * DPH + dl];
                xT[dl + 0][row] = v.x; xT[dl + 1][row] = v.y;
                xT[dl + 2][row] = v.z; xT[dl + 3][row] = v.w;
            }
        }
        {
#pragma unroll
            for (int it = 0; it < 4; ++it) {
                const int o4 = t + it * 256;
                const int dl = o4 >> 5, c4 = (o4 & 31) << 2;
                float4 v = *(const float4*)&w[(size_t)(p * DPH + dl) * KDIM + kbase + c4];
                *(float4*)&wl[dl][c4] = v;
            }
        }
        __syncthreads();
#pragma unroll 4
        for (int d = 0; d < DPH; ++d) {
            float4 xa = *(const float4*)&xT[d][xoff];
            float4 xb = *(const float4*)&xT[d][xoff + 4];
            float4 wa = *(const float4*)&wl[d][coff];
            float4 wb = *(const float4*)&wl[d][coff + 4];
            v2f wv0 = {wa.x, wa.y}, wv1 = {wa.z, wa.w};
            v2f wv2 = {wb.x, wb.y}, wv3 = {wb.z, wb.w};
            float xrr[8] = {xa.x, xa.y, xa.z, xa.w, xb.x, xb.y, xb.z, xb.w};
#pragma unroll
            for (int i = 0; i < 8; ++i) {
                v2f xs = {xrr[i], xrr[i]};
                acc[i][0] = __builtin_elementwise_fma(xs, wv0, acc[i][0]);
                acc[i][1] = __builtin_elementwise_fma(xs, wv1, acc[i][1]);
                acc[i][2] = __builtin_elementwise_fma(xs, wv2, acc[i][2]);
                acc[i][3] = __builtin_elementwise_fma(xs, wv3, acc[i][3]);
            }
        }
        __syncthreads();
    }
    const int kc = kbase + coff;
    float4 qa = *(const float4*)&wsq[kc];
    float4 qb = *(const float4*)&wsq[kc + 4];
    v2f q2[4] = {{qa.x, qa.y}, {qa.z, qa.w}, {qb.x, qb.y}, {qb.z, qb.w}};
    const v2f neg2 = {-2.f, -2.f};
#pragma unroll
    for (int i = 0; i < 8; ++i) {
        float sc[8];
#pragma unroll
        for (int jj = 0; jj < 4; ++jj) {
            v2f s2 = __builtin_elementwise_fma(neg2, acc[i][jj], q2[jj]);
            sc[2 * jj] = s2.x; sc[2 * jj + 1] = s2.y;
        }
        float bestv = sc[0]; int bj = 0;
#pragma unroll
        for (int j = 1; j < 8; ++j)
            if (sc[j] < bestv) { bestv = sc[j]; bj = j; }
        u64 key = ((u64)fmono(bestv) << 32) | (unsigned)(kc + bj);
        u64 o;
        o = __shfl_xor(key, 1); key = (o < key) ? o : key;
        o = __shfl_xor(key, 2); key = (o < key) ? o : key;
        o = __shfl_xor(key, 4); key = (o < key) ? o : key;
        if (cg == 0) atomicMin(&keys[rbase + xoff + i], key);
    }
}
__global__ void fb_gather(const u64* __restrict__ keys,
                          const float* __restrict__ wt,
                          float* __restrict__ out) {
    int t = blockIdx.x * blockDim.x + threadIdx.x;
    if (t >= NROWS * DDIM) return;
    int row = t >> 6;
    int d   = t & 63;
    int k   = (int)(keys[row] & 0xFFFFFFFFull);
    out[t] = wt[(size_t)k * DDIM + d];
}

// ================= launch =================

extern "C" void kernel_launch(void* const* d_in, const int* in_sizes, int n_in,
                              void* d_out, int out_size, void* d_ws, size_t ws_size,
                              hipStream_t stream) {
    const float* x = (const float*)d_in[0];   // [32768, 64]
    const float* w = (const float*)d_in[1];   // [64, 8192]
    float* out = (float*)d_out;

    char* ws = (char*)d_ws;
    const size_t OFF_WTB  = 0;               // 8192*64*2  = 1 MiB
    const size_t OFF_WSQ  = 1048576;         // 32 KiB
    const size_t OFF_XB   = 1081344;         // 32768*64*2 = 4 MiB
    const size_t OFF_LSUB = 5275648;         // 32768*128*2 = 8 MiB
    const size_t NEED     = 13664256;

    if (ws_size >= NEED) {
        ushort* wtb  = (ushort*)(ws + OFF_WTB);
        float*  wsq  = (float*)(ws + OFF_WSQ);
        ushort* xbb  = (ushort*)(ws + OFF_XB);
        ushort* lsub = (ushort*)(ws + OFF_LSUB);

        vq_prep_w<<<KDIM / 64, 256, 0, stream>>>(w, wtb, wsq);
        vq_prep_x<<<(NROWS * DDIM / 4) / 256, 256, 0, stream>>>(x, xbb);
        vq_scoreA<<<(NROWS / 128) * 32, 256, 0, stream>>>(xbb, wtb, wsq, lsub);
        vq_finish<<<NROWS / 4, 256, 0, stream>>>(x, w, wsq, lsub, out);
    } else {
        float* wt  = (float*)ws;
        float* wsq = (float*)(ws + 2097152);
        u64*   keys = (u64*)(ws + 2129920);
        fb_prep<<<KDIM / 256, 256, 0, stream>>>(w, wt, wsq);
        fb_init<<<NROWS / 256, 256, 0, stream>>>(keys);
        fb_gemm<<<(NROWS / BR) * (KDIM / BK), 256, 0, stream>>>(x, w, wsq, keys);
        fb_gather<<<(NROWS * DDIM) / 256, 256, 0, stream>>>(keys, wt, out);
    }
}

// Round 7
// 208.340 us; speedup vs baseline: 1.4324x; 1.4324x over previous
//
#include <hip/hip_runtime.h>
#include <hip/hip_bf16.h>
#include <cstdint>
#include <cstddef>

#define NROWS 32768
#define DDIM  64
#define KDIM  8192
#define NSUB  128                 // 64-k subchunks per row
#define DELTA 3.0f                // covers 2*eps_bf16score + 2*bf16_ulp(storage)

typedef float  f32x4 __attribute__((ext_vector_type(4)));
typedef short  s16x8 __attribute__((ext_vector_type(8)));
typedef unsigned long long u64;

// Swizzled bf16 layout for MFMA operands: matrix [R][64] stored as 16B chunks,
// chunk_idx(r,d) = (r>>4)*128 + (d>>5)*64 + ((d>>3)&3)*16 + (r&15)
// so a wave's frag load (tile,h) is base + lane*16B (fully coalesced), and
// lane(l15,l4) receives row (tile*16+l15), d = h*32+l4*8..+8 — identical
// content to the round-6 unswizzled loads (bit-identical numerics).

__device__ __forceinline__ uint32_t fmono(float f) {
    uint32_t u = __float_as_uint(f);
    return (u & 0x80000000u) ? ~u : (u | 0x80000000u);
}
__device__ __forceinline__ float bf2f(ushort s) {
    uint32_t u = (uint32_t)s << 16;
    return __uint_as_float(u);
}

// ================= fast path =================

// prep: w[d][k] -> swizzled wtb chunks; wsq[k] (serial ascending-d fmaf order)
__global__ void __launch_bounds__(256)
vq_prep_w(const float* __restrict__ w, ushort* __restrict__ wtb,
          float* __restrict__ wsq) {
    __shared__ float tile[64][65];
    const int kbase = blockIdx.x * 64;
    const int t = threadIdx.x, wv = t >> 6, lane = t & 63;
    const int l15 = lane & 15, l4 = (lane >> 4) & 3;
#pragma unroll
    for (int it = 0; it < 16; ++it) {
        int d = it * 4 + wv;
        tile[lane][d] = w[(size_t)d * KDIM + kbase + lane];   // coalesced
    }
    __syncthreads();
    // wave wv owns 16-row tile (kbase/16 + wv); writes 2 x 1KB coalesced blocks
#pragma unroll
    for (int h = 0; h < 2; ++h) {
        s16x8 c;
#pragma unroll
        for (int e = 0; e < 8; ++e) {
            float v = tile[wv * 16 + l15][h * 32 + l4 * 8 + e];
            __hip_bfloat16 hb = __float2bfloat16(v);
            c[e] = *(short*)&hb;
        }
        ((s16x8*)wtb)[(size_t)(blockIdx.x * 4 + wv) * 128 + h * 64 + lane] = c;
    }
    if (wv == 0) {   // lane = k within tile; serial ascending-d fmaf
        float s = 0.f;
#pragma unroll
        for (int d = 0; d < DDIM; ++d) {
            float v = tile[lane][d];
            s = fmaf(v, v, s);
        }
        wsq[kbase + lane] = s;
    }
}

// prep: x -> swizzled bf16 chunks. Wave handles 16 rows; writes coalesced 1KB.
__global__ void __launch_bounds__(256)
vq_prep_x(const float* __restrict__ x, ushort* __restrict__ xb) {
    const int t = threadIdx.x, wv = t >> 6, lane = t & 63;
    const int l15 = lane & 15, l4 = (lane >> 4) & 3;
    const int r = blockIdx.x * 64 + wv * 16 + l15;
#pragma unroll
    for (int h = 0; h < 2; ++h) {
        const float* src = &x[(size_t)r * DDIM + h * 32 + l4 * 8];
        float4 a = *(const float4*)src;
        float4 b = *(const float4*)(src + 4);
        float fv[8] = {a.x, a.y, a.z, a.w, b.x, b.y, b.z, b.w};
        s16x8 c;
#pragma unroll
        for (int e = 0; e < 8; ++e) {
            __hip_bfloat16 hb = __float2bfloat16(fv[e]);
            c[e] = *(short*)&hb;
        }
        ((s16x8*)xb)[(size_t)(blockIdx.x * 4 + wv) * 128 + h * 64 + lane] = c;
    }
}

// pass A: swapped-operand MFMA (k = C row dim -> lane-local subchunk min).
// Wave = 32 rows x 256 k; block = 4 waves (128 rows); grid = 256 x 32.
// All frag loads are contiguous 1KB wave accesses via the swizzled layout.
__global__ void __launch_bounds__(256)
vq_scoreA(const ushort* __restrict__ xb, const ushort* __restrict__ wb,
          const float* __restrict__ wsq, ushort* __restrict__ lsub) {
    const int kg    = blockIdx.x & 31;            // 32 k-groups of 256
    const int rbase = (blockIdx.x >> 5) * 128;
    const int t = threadIdx.x, wv = t >> 6, lane = t & 63;
    const int l15 = lane & 15, l4 = lane >> 4;
    const int rw    = rbase + wv * 32;            // this wave's 32 rows
    const int kbase = kg * 256;

    const s16x8* xs = (const s16x8*)xb;
    const s16x8* wsx = (const s16x8*)wb;

    // B operand = x rows (coalesced chunk loads)
    s16x8 bfrag[2][2];
#pragma unroll
    for (int rt = 0; rt < 2; ++rt)
#pragma unroll
        for (int h = 0; h < 2; ++h)
            bfrag[rt][h] = xs[(size_t)((rw >> 4) + rt) * 128 + h * 64 + lane];

    float subres[2][4];

#pragma unroll
    for (int sub = 0; sub < 4; ++sub) {
        const int kw = kbase + sub * 64;

        // A operand = w codewords (coalesced chunk loads)
        s16x8 afrag[4][2];
#pragma unroll
        for (int kt = 0; kt < 4; ++kt)
#pragma unroll
            for (int h = 0; h < 2; ++h)
                afrag[kt][h] = wsx[(size_t)((kw >> 4) + kt) * 128 + h * 64 + lane];

        // wsq for this lane's k values: k = kw + kt*16 + l4*4 + reg
        f32x4 wq[4];
#pragma unroll
        for (int kt = 0; kt < 4; ++kt)
            wq[kt] = *(const f32x4*)&wsq[kw + kt * 16 + l4 * 4];

        f32x4 acc[2][4];
#pragma unroll
        for (int rt = 0; rt < 2; ++rt)
#pragma unroll
            for (int kt = 0; kt < 4; ++kt) acc[rt][kt] = (f32x4)(0.f);

#pragma unroll
        for (int rt = 0; rt < 2; ++rt)
#pragma unroll
            for (int kt = 0; kt < 4; ++kt) {
                acc[rt][kt] = __builtin_amdgcn_mfma_f32_16x16x32_bf16(afrag[kt][0], bfrag[rt][0], acc[rt][kt], 0, 0, 0);
                acc[rt][kt] = __builtin_amdgcn_mfma_f32_16x16x32_bf16(afrag[kt][1], bfrag[rt][1], acc[rt][kt], 0, 0, 0);
            }

        // C layout: col (l15) = x-row, row (l4*4+reg) = k-in-tile.
#pragma unroll
        for (int rt = 0; rt < 2; ++rt) {
            float m = fmaf(-2.f, acc[rt][0][0], wq[0][0]);
#pragma unroll
            for (int kt = 0; kt < 4; ++kt)
#pragma unroll
                for (int r = 0; r < 4; ++r) {
                    if (kt == 0 && r == 0) continue;
                    m = fminf(m, fmaf(-2.f, acc[rt][kt][r], wq[kt][r]));
                }
            m = fminf(m, __shfl_xor(m, 16));
            m = fminf(m, __shfl_xor(m, 32));
            subres[rt][sub] = m;
        }
    }

    // pack + store: lane group l4==0 holds final mins; one ushort4 per row
    if (l4 == 0) {
#pragma unroll
        for (int rt = 0; rt < 2; ++rt) {
            ushort4 o;
            __hip_bfloat16 h;
            h = __float2bfloat16(subres[rt][0]); o.x = *(ushort*)&h;
            h = __float2bfloat16(subres[rt][1]); o.y = *(ushort*)&h;
            h = __float2bfloat16(subres[rt][2]); o.z = *(ushort*)&h;
            h = __float2bfloat16(subres[rt][3]); o.w = *(ushort*)&h;
            *(ushort4*)&lsub[(size_t)(rw + rt * 16 + l15) * NSUB + kg * 4] = o;
        }
    }
}

// finish: per-row (one wave): threshold -> ballot flags -> exact fp32 rescore of
// flagged subchunks -> fused gather. (Uses original x, w, wsq — unchanged.)
__global__ void __launch_bounds__(256)
vq_finish(const float* __restrict__ x, const float* __restrict__ w,
          const float* __restrict__ wsq, const ushort* __restrict__ lsub,
          float* __restrict__ out) {
    const int wv = threadIdx.x >> 6, lane = threadIdx.x & 63;
    const int row = blockIdx.x * 4 + wv;

    ushort2 us = *(const ushort2*)&lsub[(size_t)row * NSUB + lane * 2];   // coalesced
    float v0 = bf2f(us.x), v1 = bf2f(us.y);
    float m = fminf(v0, v1);
#pragma unroll
    for (int o = 1; o < 64; o <<= 1) m = fminf(m, __shfl_xor(m, o));
    const float thr = m + DELTA;
    u64 b0 = __ballot(v0 <= thr);   // bit s -> subchunk 2s
    u64 b1 = __ballot(v1 <= thr);   // bit s -> subchunk 2s+1

    float4 xr[16];
    const float4* xp = (const float4*)(x + (size_t)row * DDIM);
#pragma unroll
    for (int i = 0; i < 16; ++i) xr[i] = xp[i];   // wave-uniform row

    u64 best = ~0ull;
#pragma unroll
    for (int half = 0; half < 2; ++half) {
        u64 b = half ? b1 : b0;
        while (b) {                      // wave-uniform loop
            int s = __ffsll(b) - 1;
            b &= b - 1;
            int kk = (s * 2 + half) * 64 + lane;
            float a0 = 0.f, a1 = 0.f, a2 = 0.f, a3 = 0.f;
#pragma unroll
            for (int i = 0; i < 16; ++i) {
                a0 = fmaf(xr[i].x, w[(size_t)(4 * i + 0) * KDIM + kk], a0);
                a1 = fmaf(xr[i].y, w[(size_t)(4 * i + 1) * KDIM + kk], a1);
                a2 = fmaf(xr[i].z, w[(size_t)(4 * i + 2) * KDIM + kk], a2);
                a3 = fmaf(xr[i].w, w[(size_t)(4 * i + 3) * KDIM + kk], a3);
            }
            float dot = (a0 + a1) + (a2 + a3);       // same order as round-1 (matched np)
            float sc  = fmaf(-2.f, dot, wsq[kk]);
            u64 key = ((u64)fmono(sc) << 32) | (unsigned)kk;
#pragma unroll
            for (int sh = 1; sh < 64; sh <<= 1) {
                u64 o = __shfl_xor(key, sh);
                key = (o < key) ? o : key;
            }
            best = (key < best) ? key : best;        // lowest-k tie-break
        }
    }
    const int bestk = (int)(best & 0xFFFFFFFFull);
    out[(size_t)row * DDIM + lane] = w[(size_t)lane * KDIM + bestk];  // fused gather
}

// ================= fallback (round-3 fp32 path, small ws) =================

#define BR 128
#define BK 128
#define DPH 32
typedef float v2f __attribute__((ext_vector_type(2)));

__global__ void fb_prep(const float* __restrict__ w, float* __restrict__ wt,
                        float* __restrict__ wsq) {
    int k = blockIdx.x * blockDim.x + threadIdx.x;
    if (k >= KDIM) return;
    float s = 0.f;
#pragma unroll
    for (int d = 0; d < DDIM; ++d) {
        float v = w[(size_t)d * KDIM + k];
        wt[(size_t)k * DDIM + d] = v;
        s = fmaf(v, v, s);
    }
    wsq[k] = s;
}
__global__ void fb_init(u64* __restrict__ keys) {
    int i = blockIdx.x * blockDim.x + threadIdx.x;
    if (i < NROWS) keys[i] = ~0ull;
}
__global__ void __launch_bounds__(256, 4)
fb_gemm(const float* __restrict__ x, const float* __restrict__ w,
        const float* __restrict__ wsq, u64* __restrict__ keys) {
    __shared__ float xT[DPH][BR];
    __shared__ float wl[DPH][BK];
    const int kblk  = blockIdx.x & (KDIM / BK - 1);
    const int rbase = (blockIdx.x >> 6) * BR;
    const int kbase = kblk * BK;
    const int t     = threadIdx.x;
    const int wave = t >> 6, lane = t & 63;
    const int rg = lane >> 3, cg = lane & 7;
    const int xoff = (wave >> 1) * 64 + rg * 8;
    const int coff = (wave & 1) * 64 + cg * 8;
    v2f acc[8][4];
#pragma unroll
    for (int i = 0; i < 8; ++i)
#pragma unroll
        for (int j = 0; j < 4; ++j) acc[i][j] = (v2f)(0.f);
#pragma unroll
    for (int p = 0; p < 2; ++p) {
        {
            const int row = t & 127, dgrp = t >> 7;
#pragma unroll
            for (int it = 0; it < 4; ++it) {
                const int dl = (dgrp + it * 2) * 4;
                float4 v = *(const float4*)&x[(size_t)(rbase + row) * DDIM + p * DPH + dl];
                xT[dl + 0][row] = v.x; xT[dl + 1][row] = v.y;
                xT[dl + 2][row] = v.z; xT[dl + 3][row] = v.w;
            }
        }
        {
#pragma unroll
            for (int it = 0; it < 4; ++it) {
                const int o4 = t + it * 256;
                const int dl = o4 >> 5, c4 = (o4 & 31) << 2;
                float4 v = *(const float4*)&w[(size_t)(p * DPH + dl) * KDIM + kbase + c4];
                *(float4*)&wl[dl][c4] = v;
            }
        }
        __syncthreads();
#pragma unroll 4
        for (int d = 0; d < DPH; ++d) {
            float4 xa = *(const float4*)&xT[d][xoff];
            float4 xb = *(const float4*)&xT[d][xoff + 4];
            float4 wa = *(const float4*)&wl[d][coff];
            float4 wb = *(const float4*)&wl[d][coff + 4];
            v2f wv0 = {wa.x, wa.y}, wv1 = {wa.z, wa.w};
            v2f wv2 = {wb.x, wb.y}, wv3 = {wb.z, wb.w};
            float xrr[8] = {xa.x, xa.y, xa.z, xa.w, xb.x, xb.y, xb.z, xb.w};
#pragma unroll
            for (int i = 0; i < 8; ++i) {
                v2f xs = {xrr[i], xrr[i]};
                acc[i][0] = __builtin_elementwise_fma(xs, wv0, acc[i][0]);
                acc[i][1] = __builtin_elementwise_fma(xs, wv1, acc[i][1]);
                acc[i][2] = __builtin_elementwise_fma(xs, wv2, acc[i][2]);
                acc[i][3] = __builtin_elementwise_fma(xs, wv3, acc[i][3]);
            }
        }
        __syncthreads();
    }
    const int kc = kbase + coff;
    float4 qa = *(const float4*)&wsq[kc];
    float4 qb = *(const float4*)&wsq[kc + 4];
    v2f q2[4] = {{qa.x, qa.y}, {qa.z, qa.w}, {qb.x, qb.y}, {qb.z, qb.w}};
    const v2f neg2 = {-2.f, -2.f};
#pragma unroll
    for (int i = 0; i < 8; ++i) {
        float sc[8];
#pragma unroll
        for (int jj = 0; jj < 4; ++jj) {
            v2f s2 = __builtin_elementwise_fma(neg2, acc[i][jj], q2[jj]);
            sc[2 * jj] = s2.x; sc[2 * jj + 1] = s2.y;
        }
        float bestv = sc[0]; int bj = 0;
#pragma unroll
        for (int j = 1; j < 8; ++j)
            if (sc[j] < bestv) { bestv = sc[j]; bj = j; }
        u64 key = ((u64)fmono(bestv) << 32) | (unsigned)(kc + bj);
        u64 o;
        o = __shfl_xor(key, 1); key = (o < key) ? o : key;
        o = __shfl_xor(key, 2); key = (o < key) ? o : key;
        o = __shfl_xor(key, 4); key = (o < key) ? o : key;
        if (cg == 0) atomicMin(&keys[rbase + xoff + i], key);
    }
}
__global__ void fb_gather(const u64* __restrict__ keys,
                          const float* __restrict__ wt,
                          float* __restrict__ out) {
    int t = blockIdx.x * blockDim.x + threadIdx.x;
    if (t >= NROWS * DDIM) return;
    int row = t >> 6;
    int d   = t & 63;
    int k   = (int)(keys[row] & 0xFFFFFFFFull);
    out[t] = wt[(size_t)k * DDIM + d];
}

// ================= launch =================

extern "C" void kernel_launch(void* const* d_in, const int* in_sizes, int n_in,
                              void* d_out, int out_size, void* d_ws, size_t ws_size,
                              hipStream_t stream) {
    const float* x = (const float*)d_in[0];   // [32768, 64]
    const float* w = (const float*)d_in[1];   // [64, 8192]
    float* out = (float*)d_out;

    char* ws = (char*)d_ws;
    const size_t OFF_WTB  = 0;               // 8192*64*2  = 1 MiB (swizzled)
    const size_t OFF_WSQ  = 1048576;         // 32 KiB
    const size_t OFF_XB   = 1081344;         // 32768*64*2 = 4 MiB (swizzled)
    const size_t OFF_LSUB = 5275648;         // 32768*128*2 = 8 MiB
    const size_t NEED     = 13664256;

    if (ws_size >= NEED) {
        ushort* wtb  = (ushort*)(ws + OFF_WTB);
        float*  wsq  = (float*)(ws + OFF_WSQ);
        ushort* xbb  = (ushort*)(ws + OFF_XB);
        ushort* lsub = (ushort*)(ws + OFF_LSUB);

        vq_prep_w<<<KDIM / 64, 256, 0, stream>>>(w, wtb, wsq);
        vq_prep_x<<<NROWS / 64, 256, 0, stream>>>(x, xbb);
        vq_scoreA<<<(NROWS / 128) * 32, 256, 0, stream>>>(xbb, wtb, wsq, lsub);
        vq_finish<<<NROWS / 4, 256, 0, stream>>>(x, w, wsq, lsub, out);
    } else {
        float* wt  = (float*)ws;
        float* wsq = (float*)(ws + 2097152);
        u64*   keys = (u64*)(ws + 2129920);
        fb_prep<<<KDIM / 256, 256, 0, stream>>>(w, wt, wsq);
        fb_init<<<NROWS / 256, 256, 0, stream>>>(keys);
        fb_gemm<<<(NROWS / BR) * (KDIM / BK), 256, 0, stream>>>(x, w, wsq, keys);
        fb_gather<<<(NROWS * DDIM) / 256, 256, 0, stream>>>(keys, wt, out);
    }
}